// Round 4
// baseline (85.136 us; speedup 1.0000x reference)
//
#include <hip/hip_runtime.h>
#include <hip/hip_bf16.h>

#define CELLS 1000   // 10*10*10
#define DPB   16     // depos per group
#define NTH   512

typedef float vfloat4 __attribute__((ext_vector_type(4)));

// Persistent grid-stride kernel, double-buffered LDS pipeline.
// Per group g (16 depos):
//   phase1: threads 0..479 compute w[d][dim*10+k] from PRELOADED regs -> wq[buf]
//   raw s_barrier (no vmcnt drain -- stores stay in flight)
//   preload next group's inputs into regs (latency hides under store burst)
//   store : threads 0..499 write 8 x float4 nontemporal (32 KB/group)
// Double buffer => one barrier per group is sufficient:
// reads of wq[b] in group i are separated from writes of wq[b] in group i+2
// by group i+1's barrier.
__global__ __launch_bounds__(NTH) void raster_kernel(
    const float* __restrict__ sigma,   // [N,3]
    const float* __restrict__ time,    // [N]
    const float* __restrict__ charge,  // [N]
    const float* __restrict__ tail,    // [N,3]
    const float* __restrict__ gs,      // [3]
    const float* __restrict__ nsig,    // [1]
    float* __restrict__ out_r,         // [N,10,10,10]
    float* __restrict__ out_off,       // [N,3] (int values stored as f32)
    int n, int ngroups)
{
    const int tid = threadIdx.x;

    __shared__ float wq[2][DPB][32];   // [buf][d][0..29]=w, [30]=charge

    // ---- fixed thread roles ----
    const bool p1     = (tid < DPB * 30);
    const int  p1_d   = tid / 30;
    const int  p1_r   = tid - p1_d * 30;
    const int  p1_dim = p1_r / 10;
    const int  p1_k   = p1_r - p1_dim * 10;

    const bool st   = (tid < 500);
    const int  half = (tid >= 250) ? 1 : 0;
    const int  c4   = tid - 250 * half;
    int a0[4], a1[4], a2[4];
#pragma unroll
    for (int c = 0; c < 4; ++c) {
        const int cell = c4 * 4 + c;
        a0[c] = cell / 100;
        a1[c] = 10 + (cell / 10) % 10;
        a2[c] = 20 + cell % 10;
    }

    const float ns = nsig[0];
    const float sp = p1 ? gs[p1_dim] : 0.5f;

    // ---- preload group 0 inputs ----
    float c_nx = 0.f, sg_nx = 1.f, q_nx = 0.f;
    int g = blockIdx.x;
    if (p1 && g < ngroups) {
        const int depo = g * DPB + p1_d;
        if (depo < n) {
            c_nx  = (p1_dim == 0) ? tail[depo * 3 + 1]
                  : (p1_dim == 1) ? tail[depo * 3 + 2]
                  : time[depo];
            sg_nx = sigma[depo * 3 + p1_dim];
            if (p1_r == 0) q_nx = charge[depo];
        }
    }

    int buf = 0;
    for (; g < ngroups; g += gridDim.x) {
        // ---- phase 1: w into wq[buf] from preloaded regs ----
        if (p1) {
            const int depo = g * DPB + p1_d;
            if (depo < n) {
                const float imin = floorf((c_nx - ns * sg_nx) / sp);
                const float inv  = 1.0f / (1.41421356237309f * sg_nx);
                const float e0   = (imin + (float)p1_k) * sp;
                const float e1   = e0 + sp;
                const float cdf0 = 0.5f * (1.0f + erff((e0 - c_nx) * inv));
                const float cdf1 = 0.5f * (1.0f + erff((e1 - c_nx) * inv));
                wq[buf][p1_d][p1_dim * 10 + p1_k] = cdf1 - cdf0;
                if (p1_k == 0) {
                    out_off[(size_t)depo * 3 + p1_dim] = (float)(int)imin;
                    if (p1_dim == 0) wq[buf][p1_d][30] = q_nx;
                }
            }
        }
        // drain own LDS writes, then raw barrier (stores stay in flight)
        asm volatile("s_waitcnt lgkmcnt(0)" ::: "memory");
        __builtin_amdgcn_s_barrier();
        asm volatile("" ::: "memory");

        // ---- preload next group's inputs (loads in flight during stores) ----
        const int gn = g + gridDim.x;
        if (p1 && gn < ngroups) {
            const int depo = gn * DPB + p1_d;
            if (depo < n) {
                c_nx  = (p1_dim == 0) ? tail[depo * 3 + 1]
                      : (p1_dim == 1) ? tail[depo * 3 + 2]
                      : time[depo];
                sg_nx = sigma[depo * 3 + p1_dim];
                if (p1_r == 0) q_nx = charge[depo];
            }
        }

        // ---- store burst: 32 KB of nontemporal float4 ----
        if (st) {
#pragma unroll
            for (int it = 0; it < DPB / 2; ++it) {
                const int d    = it * 2 + half;
                const int depo = g * DPB + d;
                if (depo < n) {
                    const float q = wq[buf][d][30];
                    vfloat4 v;
                    v.x = q * wq[buf][d][a0[0]] * wq[buf][d][a1[0]] * wq[buf][d][a2[0]];
                    v.y = q * wq[buf][d][a0[1]] * wq[buf][d][a1[1]] * wq[buf][d][a2[1]];
                    v.z = q * wq[buf][d][a0[2]] * wq[buf][d][a1[2]] * wq[buf][d][a2[2]];
                    v.w = q * wq[buf][d][a0[3]] * wq[buf][d][a1[3]] * wq[buf][d][a2[3]];
                    vfloat4* dst =
                        reinterpret_cast<vfloat4*>(out_r + (size_t)depo * CELLS) + c4;
                    __builtin_nontemporal_store(v, dst);
                }
            }
        }
        buf ^= 1;
    }
}

extern "C" void kernel_launch(void* const* d_in, const int* in_sizes, int n_in,
                              void* d_out, int out_size, void* d_ws, size_t ws_size,
                              hipStream_t stream) {
    const float* sigma  = (const float*)d_in[0];  // [N,3]
    const float* time_  = (const float*)d_in[1];  // [N]
    const float* charge = (const float*)d_in[2];  // [N]
    const float* tail   = (const float*)d_in[3];  // [N,3]
    const float* gs     = (const float*)d_in[4];  // [3]
    const float* nsig   = (const float*)d_in[5];  // [1]

    const int n = in_sizes[1];  // time has N elements

    float* out_r   = (float*)d_out;                       // N*1000 floats
    float* out_off = (float*)d_out + (size_t)n * CELLS;   // N*3 values

    const int ngroups = (n + DPB - 1) / DPB;
    int grid = ngroups < 1024 ? ngroups : 1024;           // ~4 blocks/CU resident
    raster_kernel<<<grid, NTH, 0, stream>>>(sigma, time_, charge, tail, gs, nsig,
                                            out_r, out_off, n, ngroups);
}

// Round 5
// 82.553 us; speedup vs baseline: 1.0313x; 1.0313x over previous
//
#include <hip/hip_runtime.h>
#include <hip/hip_bf16.h>

#define CELLS 1000   // 10*10*10
#define DPB   16     // depos per block (100000 % 16 == 0 -> 6250 blocks)
#define NTH   512

typedef float vfloat4 __attribute__((ext_vector_type(4)));

// One group of 16 depos per 512-thread block, 3 phases:
//  phase 1  (480 thr): w[d][dim*10+k]; dim0 weights pre-multiplied by charge.
//  phase 1.5(512 thr): qw01[d][ij] = (q*w0[i]) * w1[j]  (100 per depo).
//  store    (500 thr): per float4 only 6 LDS reads (2 qw01 + 4 w2) instead of
//                      13 -- LDS issue was capping value production below the
//                      HBM write rate. k-indices / wrap flags are loop-invariant.
__global__ __launch_bounds__(NTH) void raster_kernel(
    const float* __restrict__ sigma,   // [N,3]
    const float* __restrict__ time,    // [N]
    const float* __restrict__ charge,  // [N]
    const float* __restrict__ tail,    // [N,3]
    const float* __restrict__ gs,      // [3]
    const float* __restrict__ nsig,    // [1]
    float* __restrict__ out_r,         // [N,10,10,10]
    float* __restrict__ out_off,       // [N,3] (int values stored as f32)
    int n)
{
    const int d0  = blockIdx.x * DPB;
    const int tid = threadIdx.x;

    __shared__ float w[DPB][32];      // [0..9]=q*w0, [10..19]=w1, [20..29]=w2
    __shared__ float qw01[DPB][104];  // [ij]=q*w0[i]*w1[j], padded stride

    // ---- phase 1 ----
    if (tid < DPB * 30) {
        const int d   = tid / 30;
        const int r   = tid - d * 30;
        const int dim = r / 10;
        const int k   = r - dim * 10;
        const int depo = d0 + d;
        if (depo < n) {
            float c;
            if (dim == 0)      c = tail[depo * 3 + 1];
            else if (dim == 1) c = tail[depo * 3 + 2];
            else               c = time[depo];
            const float sg = sigma[depo * 3 + dim];
            const float sp = gs[dim];
            const float ns = nsig[0];
            const float imin = floorf((c - ns * sg) / sp);
            const float inv  = 1.0f / (1.41421356237309f * sg);
            const float e0   = (imin + (float)k) * sp;
            const float cdf0 = 0.5f * (1.0f + erff((e0 - c) * inv));
            const float cdf1 = 0.5f * (1.0f + erff((e0 + sp - c) * inv));
            float wv = cdf1 - cdf0;
            if (dim == 0) wv *= charge[depo];       // fold q into dim-0 weights
            w[d][dim * 10 + k] = wv;
            if (k == 0) out_off[(size_t)depo * 3 + dim] = (float)(int)imin;
        }
    }
    __syncthreads();

    // ---- phase 1.5: pair products ----
#pragma unroll
    for (int idx = tid; idx < DPB * 100; idx += NTH) {
        const int d  = idx / 100;
        const int ij = idx - d * 100;
        const int i  = ij / 10;
        const int j  = ij - i * 10;
        qw01[d][ij] = w[d][i] * w[d][10 + j];
    }
    __syncthreads();

    // ---- store phase ----
    if (tid < 500) {
        const int half = (tid >= 250) ? 1 : 0;
        const int c4   = tid - 250 * half;       // float4 index within depo
        const int c0   = c4 * 4;
        const int ij0  = c0 / 10;
        const int k0   = c0 - ij0 * 10;

        // loop-invariant component descriptors
        int  kc[4];
        bool wr[4];
#pragma unroll
        for (int c = 0; c < 4; ++c) {
            const int kk = k0 + c;
            wr[c] = (kk >= 10);
            kc[c] = 20 + (wr[c] ? kk - 10 : kk);
        }
        // note: when wrap occurs ij0+1 <= 99; when ij0==99 no wrap occurs and
        // qw01[d][100] is a harmless in-bounds-of-array dummy read.

#pragma unroll
        for (int it = 0; it < DPB / 2; ++it) {
            const int d    = it * 2 + half;
            const int depo = d0 + d;
            if (depo < n) {
                const float r0 = qw01[d][ij0];
                const float r1 = qw01[d][ij0 + 1];
                vfloat4 v;
                v.x = (wr[0] ? r1 : r0) * w[d][kc[0]];
                v.y = (wr[1] ? r1 : r0) * w[d][kc[1]];
                v.z = (wr[2] ? r1 : r0) * w[d][kc[2]];
                v.w = (wr[3] ? r1 : r0) * w[d][kc[3]];
                vfloat4* dst =
                    reinterpret_cast<vfloat4*>(out_r + (size_t)depo * CELLS) + c4;
                __builtin_nontemporal_store(v, dst);
            }
        }
    }
}

extern "C" void kernel_launch(void* const* d_in, const int* in_sizes, int n_in,
                              void* d_out, int out_size, void* d_ws, size_t ws_size,
                              hipStream_t stream) {
    const float* sigma  = (const float*)d_in[0];  // [N,3]
    const float* time_  = (const float*)d_in[1];  // [N]
    const float* charge = (const float*)d_in[2];  // [N]
    const float* tail   = (const float*)d_in[3];  // [N,3]
    const float* gs     = (const float*)d_in[4];  // [3]
    const float* nsig   = (const float*)d_in[5];  // [1]

    const int n = in_sizes[1];  // time has N elements

    float* out_r   = (float*)d_out;                       // N*1000 floats
    float* out_off = (float*)d_out + (size_t)n * CELLS;   // N*3 values

    const int grid = (n + DPB - 1) / DPB;
    raster_kernel<<<grid, NTH, 0, stream>>>(sigma, time_, charge, tail, gs, nsig,
                                            out_r, out_off, n);
}